// Round 9
// baseline (16068.533 us; speedup 1.0000x reference)
//
#include <hip/hip_runtime.h>

#define D 100
#define TT 2048
#define BB 128
#define CHUNK 64
#define NCHUNK (TT / CHUNK)  /* 32 */
#define NTHR 896             /* 14 waves: 0=consumer, 1..12=producers, 13=stager */

static __device__ __constant__ float KLO = 2.8853900817779268f;   // 2*log2(e)
static __device__ __constant__ float MKF = -2.8853900817779268f;  // -2*log2(e)

// q += dpp_shuffle(q); ctrl must be an immediate
#define DPP_ADD(q, ctrl)                                                      \
  q += __int_as_float(__builtin_amdgcn_update_dpp(                            \
      0, __float_as_int(q), ctrl, 0xF, 0xF, true))

// ---------------------------------------------------------------------------
// K1: ab2m[j] = -log2(e) * (pos_table[j] . w_ap + b0)
// ---------------------------------------------------------------------------
__global__ void k1_pos(const float* __restrict__ pos, const float* __restrict__ wap,
                       const float* __restrict__ bb, float* __restrict__ ab2m) {
  int j = blockIdx.x * blockDim.x + threadIdx.x;
  if (j < TT) {
    float a = 0.f;
    #pragma unroll 4
    for (int e = 0; e < D; ++e) a = fmaf(pos[j * D + e], wap[e], a);
    ab2m[j] = -1.4426950408889634f * (a + bb[0]);
  }
}

// ---------------------------------------------------------------------------
// Fused scan, one block (14 waves) per batch row.
//   wave 0      : sequential chain — ALL steady-state reads from LDS/regs
//                 (R5's 648cy/step was the chain's own global prefetch stalls)
//   waves 1..12 : R5-VERBATIM producers: wlo/whi per-lane full rows, global-h
//                 float4 dots (R5 proved: remat, no scratch-writes, and 4x
//                 redundant coverage still kept pace -> headroom)
//   wave 13     : stages h chunk cc+2 into hstage ring for the consumer
// R8 lessons honored: no per-lane acc arrays, no row-strided LDS W.
// ---------------------------------------------------------------------------
__global__ void __launch_bounds__(NTHR)
sp_scan(const float* __restrict__ h, const float* __restrict__ dv,
        const float* __restrict__ w_c, const float* __restrict__ w_s,
        const float* __restrict__ w_r, const float* __restrict__ ab2m,
        float* __restrict__ out) {
  __shared__ float gbuf[2][CHUNK][128];                  // 64 KiB
  __shared__ __align__(16) float hstage[3][CHUNK][104];  // 78 KiB
  const int b = blockIdx.x;
  const int tid = (int)threadIdx.x;
  const int lane = tid & 63;
  const int wvu = __builtin_amdgcn_readfirstlane(tid) >> 6;  // 0..13
  float* crow_s = &gbuf[0][0][0];  // overlay; consumed before first produce
  const float* hb = h + (size_t)b * TT * D;

  // ---- P1: crow[e] partials (tid<128, serial) | stager stages chunk 0 -----
  if (wvu == 13) {
    for (int s = 0; s < CHUNK; ++s) {
      const float* hr = hb + (size_t)s * D;
      hstage[0][s][lane] = hr[lane];
      if (lane < 36) hstage[0][s][64 + lane] = hr[64 + lane];
    }
  } else if (tid < 128) {
    float acc = 0.f;
    if (tid < D) {
      float a1 = 0.f, a2 = 0.f;
      for (int dd = 0; dd < D; ++dd) {
        a1 = fmaf(dv[b * D + dd], w_s[dd * D + tid], a1);
        a2 += w_r[dd * D + tid];
      }
      acc = w_c[tid] + a1 - a2;
    }
    crow_s[tid] = acc;
  }
  __syncthreads();

  // ---- P2: producers pull their two w_r rows (R5 verbatim) | stage chunk 1
  float wlo[D], whi[D];
  if (wvu >= 1 && wvu <= 12) {
    const float* rl = w_r + lane * D;
    #pragma unroll
    for (int e = 0; e < D; ++e) wlo[e] = rl[e];
    if (lane < 36) {
      const float* rh_ = w_r + (lane + 64) * D;
      #pragma unroll
      for (int e = 0; e < D; ++e) whi[e] = rh_[e];
    } else if (lane == 36) {
      #pragma unroll
      for (int e = 0; e < D; ++e) whi[e] = crow_s[e];  // synthetic row 100
    } else {
      #pragma unroll
      for (int e = 0; e < D; ++e) whi[e] = 0.f;        // pad rows 101..127
    }
  } else if (wvu == 13) {
    const float* hc = hb + (size_t)CHUNK * D;
    for (int s = 0; s < CHUNK; ++s) {
      const float* hr = hc + (size_t)s * D;
      hstage[1][s][lane] = hr[lane];
      if (lane < 36) hstage[1][s][64 + lane] = hr[64 + lane];
    }
  }
  __syncthreads();

  const int q = wvu - 1;
  const int grp = q >> 2;  // 3 step-groups, 4x redundant coverage (R5 artifact)

  // R5-verbatim producer body: full-row dots from GLOBAL h
  auto produce = [&](float (*gw)[128], int jbase) {
    for (int s = grp; s < CHUNK; s += 3) {
      const float4* hr = (const float4*)(hb + (size_t)(jbase + s) * D);
      float a0 = 0.f, a1 = 0.f, c0 = 0.f, c1 = 0.f;
      #pragma unroll
      for (int qd = 0; qd < 25; ++qd) {
        const float4 hv = hr[qd];
        a0 = fmaf(hv.x, wlo[4 * qd + 0], a0);
        a1 = fmaf(hv.y, wlo[4 * qd + 1], a1);
        a0 = fmaf(hv.z, wlo[4 * qd + 2], a0);
        a1 = fmaf(hv.w, wlo[4 * qd + 3], a1);
        c0 = fmaf(hv.x, whi[4 * qd + 0], c0);
        c1 = fmaf(hv.y, whi[4 * qd + 1], c1);
        c0 = fmaf(hv.z, whi[4 * qd + 2], c0);
        c1 = fmaf(hv.w, whi[4 * qd + 3], c1);
      }
      gw[s][lane] = a0 + a1;
      gw[s][lane + 64] = c0 + c1;
    }
  };

  // consumer state
  float Slo = 0.f, Shi = 0.f, c = 0.f, hlp = 0.f, hhp = 0.f, pout = 0.f;
  float hlr0 = 0.f, hlr1 = 0.f, hhr0 = 0.f, hhr1 = 0.f, abrow_ = 0.f;

  // ---- P3: produce chunk 0 | consumer primes (LDS) | stager idle ----------
  if (wvu == 0) {
    __builtin_amdgcn_s_setprio(1);
    abrow_ = ab2m[lane];
    hlr0 = hstage[0][0][lane];
    hlr1 = hstage[0][1][lane];
    if (lane < 36) { hhr0 = hstage[0][0][64 + lane]; hhr1 = hstage[0][1][64 + lane]; }
  } else if (wvu <= 12) {
    produce(gbuf[0], 0);
  }
  __syncthreads();

  // ---- main loop: 32 chunks of 64 steps -----------------------------------
  int bufc = 0;  // cc % 3
  for (int cc = 0; cc < NCHUNK; ++cc) {
    const int bufn = (bufc == 2) ? 0 : bufc + 1;
    if (wvu == 0) {
      float (*gb)[128] = gbuf[cc & 1];
      float g0l = gb[0][lane], g0h = gb[0][64 + lane];
      float g1l = gb[1][lane], g1h = gb[1][64 + lane];
      const int ncc = (cc + 1 < NCHUNK) ? cc + 1 : cc;
      float abn = ab2m[ncc * CHUNK + lane];  // next chunk's ab row (off-chain)
      const bool notlast = (cc != NCHUNK - 1);
      #pragma unroll 8
      for (int s = 0; s < CHUNK; ++s) {
        // h ring refill (row s+2; crosses into next chunk's buffer)
        float hlN = 0.f, hhN = 0.f;
        if (s < CHUNK - 2) {
          const float* hr = &hstage[bufc][s + 2][0];
          hlN = hr[lane];
          if (lane < 36) hhN = hr[64 + lane];
        } else if (notlast) {
          const float* hr = &hstage[bufn][s + 2 - CHUNK][0];
          hlN = hr[lane];
          if (lane < 36) hhN = hr[64 + lane];
        }
        // g prefetch, distance 2
        float g2l = 0.f, g2h = 0.f;
        if (s < CHUNK - 2) { g2l = gb[s + 2][lane]; g2h = gb[s + 2][64 + lane]; }

        // ---- the sequential chain (no memory ops) ----
        Slo = fmaf(hlp, c, Slo);
        Shi = fmaf(hhp, c, Shi);
        float rlo = __builtin_amdgcn_rcpf(1.f + __builtin_amdgcn_exp2f(Slo));
        float rhi = __builtin_amdgcn_rcpf(1.f + __builtin_amdgcn_exp2f(Shi));
        float qq = rlo * g0l;
        qq = fmaf(rhi, g0h, qq);
        DPP_ADD(qq, 0xB1);   // + lane^1
        DPP_ADD(qq, 0x4E);   // + lane^2
        DPP_ADD(qq, 0x141);  // row_half_mirror -> 8-sums
        DPP_ADD(qq, 0x140);  // row_mirror      -> 16-sums
        const int qi = __float_as_int(qq);
        float ra = __int_as_float(__builtin_amdgcn_readlane(qi, 0)) +
                   __int_as_float(__builtin_amdgcn_readlane(qi, 16));
        float rb = __int_as_float(__builtin_amdgcn_readlane(qi, 32)) +
                   __int_as_float(__builtin_amdgcn_readlane(qi, 48));
        float R = ra + rb;
        float abv = __int_as_float(
            __builtin_amdgcn_readlane(__float_as_int(abrow_), s));
        float nz = fmaf(MKF, R, abv);
        float p = __builtin_amdgcn_rcpf(1.f + __builtin_amdgcn_exp2f(nz));
        pout = (lane == s) ? p : pout;
        c = p;
        // consume ring row s, refill with row s+2 (KLO scaling off-chain)
        float hl_cur = (s & 1) ? hlr1 : hlr0;
        float hh_cur = (s & 1) ? hhr1 : hhr0;
        hlp = KLO * hl_cur;
        hhp = KLO * hh_cur;
        if (s == 0 && cc == 0) { hlp = 0.f; hhp = 0.f; }  // j==0 mask
        if (s & 1) { hlr1 = hlN; hhr1 = hhN; } else { hlr0 = hlN; hhr0 = hhN; }
        g0l = g1l; g0h = g1h; g1l = g2l; g1h = g2h;
      }
      out[(size_t)b * TT + cc * CHUNK + lane] = pout;
      abrow_ = abn;
    } else if (wvu <= 12) {
      if (cc + 1 < NCHUNK) produce(gbuf[(cc + 1) & 1], (cc + 1) * CHUNK);
    } else {
      if (cc + 2 < NCHUNK) {
        const int bufs = (bufn == 2) ? 0 : bufn + 1;
        const float* hc = hb + (size_t)(cc + 2) * CHUNK * D;
        for (int s = 0; s < CHUNK; ++s) {
          const float* hr = hc + (size_t)s * D;
          hstage[bufs][s][lane] = hr[lane];
          if (lane < 36) hstage[bufs][s][64 + lane] = hr[64 + lane];
        }
      }
    }
    __syncthreads();
    bufc = bufn;
  }
}

extern "C" void kernel_launch(void* const* d_in, const int* in_sizes, int n_in,
                              void* d_out, int out_size, void* d_ws, size_t ws_size,
                              hipStream_t stream) {
  const float* h   = (const float*)d_in[0];
  const float* dv  = (const float*)d_in[1];
  const float* w_c = (const float*)d_in[2];
  const float* w_s = (const float*)d_in[3];
  const float* w_r = (const float*)d_in[4];
  const float* pos = (const float*)d_in[5];
  const float* wap = (const float*)d_in[6];
  const float* bb  = (const float*)d_in[7];
  float* out = (float*)d_out;
  float* ab2m = (float*)d_ws;  // 2048 floats

  hipLaunchKernelGGL(k1_pos, dim3(TT / 256), dim3(256), 0, stream, pos, wap, bb, ab2m);
  hipLaunchKernelGGL(sp_scan, dim3(BB), dim3(NTHR), 0, stream,
                     h, dv, w_c, w_s, w_r, ab2m, out);
}

// Round 10
// 788.893 us; speedup vs baseline: 20.3685x; 20.3685x over previous
//
#include <hip/hip_runtime.h>

#define D 100
#define TT 2048
#define BB 128
#define CHUNK 32
#define NCHUNK (TT / CHUNK)  /* 64 */
#define NTHR 384             /* 6 waves: 0=consumer, 1=stager, 2..5=producers */
#define HS 33                /* hT s-stride: odd => conflict-free + no vector-merge */

static __device__ __constant__ float KLO = 2.8853900817779268f;   // 2*log2(e)
static __device__ __constant__ float MKF = -2.8853900817779268f;  // -2*log2(e)

// q += dpp_shuffle(q); ctrl must be an immediate
#define DPP_ADD(q, ctrl)                                                      \
  q += __int_as_float(__builtin_amdgcn_update_dpp(                            \
      0, __float_as_int(q), ctrl, 0xF, 0xF, true))

// ---------------------------------------------------------------------------
// K1: ab2m[j] = -log2(e) * (pos_table[j] . w_ap + b0)
// ---------------------------------------------------------------------------
__global__ void k1_pos(const float* __restrict__ pos, const float* __restrict__ wap,
                       const float* __restrict__ bb, float* __restrict__ ab2m) {
  int j = blockIdx.x * blockDim.x + threadIdx.x;
  if (j < TT) {
    float a = 0.f;
    #pragma unroll 4
    for (int e = 0; e < D; ++e) a = fmaf(pos[j * D + e], wap[e], a);
    ab2m[j] = -1.4426950408889634f * (a + bb[0]);
  }
}

// ---------------------------------------------------------------------------
// R10: allocator-proof fused scan. Lesson of R1-R9: this kernel's VGPR budget
// is pinned at ~64 and ANY per-lane bulk array spills (or remat-reloads) with
// catastrophic scratch traffic. So: ALL bulk data in LDS, conflict-free
// layouts, every wave role <= ~30 live VGPRs.
//   W_t[e][c] = W'[c][e]  (W' rows: w_r rows 0..99, crow at 100, zero pad)
//     producer read W_t[e][lane] -> bank lane%32, conflict-free.
//   hT[buf][e][s], s-stride 33 (odd): producer h reads are broadcasts;
//     consumer/stager per-lane accesses hit distinct banks.
//   wave 0: sequential chain (proven R7/R9 code; zero global/gbuf-partial ops)
//   wave 1: stages h chunk cc+2 (coalesced global -> conflict-free LDS)
//   waves 2-5: g = W' @ h_s: per e, 2 LDS reads + 8 broadcasts + 16 FMAs into
//     16 NAMED accumulators (8 s-values x 2 cols). ~25 live regs.
// ---------------------------------------------------------------------------
__global__ void __launch_bounds__(NTHR)
sp_scan(const float* __restrict__ h, const float* __restrict__ dv,
        const float* __restrict__ w_c, const float* __restrict__ w_s,
        const float* __restrict__ w_r, const float* __restrict__ ab2m,
        float* __restrict__ out) {
  __shared__ float W_t[D][128];          // 51.2 KiB
  __shared__ float gbuf[2][CHUNK][128];  // 32 KiB
  __shared__ float hT[3][D][HS];         // 39.6 KiB
  const int b = blockIdx.x;
  const int tid = (int)threadIdx.x;
  const int lane = tid & 63;
  const int wvu = __builtin_amdgcn_readfirstlane(tid) >> 6;  // 0..5
  const float* hb = h + (size_t)b * TT * D;

  // ---- phase A: fill W_t (waves 0,2,3,4,5) | stager stages chunk 0 --------
  if (wvu == 1) {
    for (int s = 0; s < CHUNK; ++s) {
      const float* hr = hb + (size_t)s * D;
      hT[0][lane][s] = hr[lane];                       // e = lane
      if (lane < 36) hT[0][64 + lane][s] = hr[64 + lane];
    }
  } else {
    const int fw = (wvu == 0) ? 0 : (wvu - 1);         // 0..4
    for (int e = fw; e < D; e += 5) {
      W_t[e][lane] = w_r[lane * D + e];                // col c = lane
      W_t[e][64 + lane] = (lane < 36) ? w_r[(64 + lane) * D + e] : 0.f;
    }
  }
  __syncthreads();

  // ---- phase B: crow -> W_t[e][100] (waves 2,3) | stager stages chunk 1 ---
  if (wvu == 1) {
    const float* hc = hb + (size_t)CHUNK * D;
    for (int s = 0; s < CHUNK; ++s) {
      const float* hr = hc + (size_t)s * D;
      hT[1][lane][s] = hr[lane];
      if (lane < 36) hT[1][64 + lane][s] = hr[64 + lane];
    }
  } else if (tid >= 128 && tid < 256) {
    const int e = tid - 128;  // 0..127
    if (e < D) {
      float a1 = 0.f, a2 = 0.f;
      #pragma unroll 4
      for (int dd = 0; dd < D; ++dd) {
        a1 = fmaf(dv[b * D + dd], w_s[dd * D + e], a1);
        a2 += w_r[dd * D + e];
      }
      W_t[e][100] = w_c[e] + a1 - a2;  // synthetic row 100 = crow
    }
  }
  __syncthreads();

  // producer body: 8 s-values (s0..s0+7), cols lane & lane+64, rank-1 updates
  const int s0 = (wvu - 2) * 8;
  auto produce = [&](float (*gw)[128], const float (*ht)[HS]) {
    float l0 = 0.f, l1 = 0.f, l2 = 0.f, l3 = 0.f,
          l4 = 0.f, l5 = 0.f, l6 = 0.f, l7 = 0.f;
    float u0 = 0.f, u1 = 0.f, u2 = 0.f, u3 = 0.f,
          u4 = 0.f, u5 = 0.f, u6 = 0.f, u7 = 0.f;
    for (int e = 0; e < D; ++e) {
      const float w0 = W_t[e][lane];
      const float w1 = W_t[e][64 + lane];
      const float* hs = &ht[e][s0];
      const float h0 = hs[0], h1 = hs[1], h2 = hs[2], h3 = hs[3];
      const float h4 = hs[4], h5 = hs[5], h6 = hs[6], h7 = hs[7];
      l0 = fmaf(w0, h0, l0); u0 = fmaf(w1, h0, u0);
      l1 = fmaf(w0, h1, l1); u1 = fmaf(w1, h1, u1);
      l2 = fmaf(w0, h2, l2); u2 = fmaf(w1, h2, u2);
      l3 = fmaf(w0, h3, l3); u3 = fmaf(w1, h3, u3);
      l4 = fmaf(w0, h4, l4); u4 = fmaf(w1, h4, u4);
      l5 = fmaf(w0, h5, l5); u5 = fmaf(w1, h5, u5);
      l6 = fmaf(w0, h6, l6); u6 = fmaf(w1, h6, u6);
      l7 = fmaf(w0, h7, l7); u7 = fmaf(w1, h7, u7);
    }
    gw[s0 + 0][lane] = l0; gw[s0 + 0][64 + lane] = u0;
    gw[s0 + 1][lane] = l1; gw[s0 + 1][64 + lane] = u1;
    gw[s0 + 2][lane] = l2; gw[s0 + 2][64 + lane] = u2;
    gw[s0 + 3][lane] = l3; gw[s0 + 3][64 + lane] = u3;
    gw[s0 + 4][lane] = l4; gw[s0 + 4][64 + lane] = u4;
    gw[s0 + 5][lane] = l5; gw[s0 + 5][64 + lane] = u5;
    gw[s0 + 6][lane] = l6; gw[s0 + 6][64 + lane] = u6;
    gw[s0 + 7][lane] = l7; gw[s0 + 7][64 + lane] = u7;
  };

  // consumer state
  float Slo = 0.f, Shi = 0.f, c = 0.f, hlp = 0.f, hhp = 0.f, pout = 0.f;
  float hlr0 = 0.f, hlr1 = 0.f, hhr0 = 0.f, hhr1 = 0.f, abrow_ = 0.f;

  // ---- phase C: produce chunk 0 | consumer primes | stager idle -----------
  if (wvu == 0) {
    __builtin_amdgcn_s_setprio(1);
    abrow_ = ab2m[lane & 31];
    hlr0 = hT[0][lane][0];
    hlr1 = hT[0][lane][1];
    if (lane < 36) { hhr0 = hT[0][64 + lane][0]; hhr1 = hT[0][64 + lane][1]; }
  } else if (wvu >= 2) {
    produce(gbuf[0], hT[0]);
  }
  __syncthreads();

  // ---- main loop: 64 chunks of 32 steps -----------------------------------
  int bufc = 0;  // cc % 3
  for (int cc = 0; cc < NCHUNK; ++cc) {
    const int bufn = (bufc == 2) ? 0 : bufc + 1;
    if (wvu == 0) {
      float (*gb)[128] = gbuf[cc & 1];
      float g0l = gb[0][lane], g0h = gb[0][64 + lane];
      float g1l = gb[1][lane], g1h = gb[1][64 + lane];
      const int ncc = (cc + 1 < NCHUNK) ? cc + 1 : cc;
      float abn = ab2m[ncc * CHUNK + (lane & 31)];
      const bool notlast = (cc != NCHUNK - 1);
      #pragma unroll
      for (int s = 0; s < CHUNK; ++s) {
        // h ring refill (row s+2; crosses into next chunk's buffer)
        float hlN = 0.f, hhN = 0.f;
        if (s < CHUNK - 2) {
          hlN = hT[bufc][lane][s + 2];
          if (lane < 36) hhN = hT[bufc][64 + lane][s + 2];
        } else if (notlast) {
          hlN = hT[bufn][lane][s + 2 - CHUNK];
          if (lane < 36) hhN = hT[bufn][64 + lane][s + 2 - CHUNK];
        }
        // g prefetch, distance 2
        float g2l = 0.f, g2h = 0.f;
        if (s < CHUNK - 2) { g2l = gb[s + 2][lane]; g2h = gb[s + 2][64 + lane]; }

        // ---- the sequential chain (register/DPP only) ----
        Slo = fmaf(hlp, c, Slo);
        Shi = fmaf(hhp, c, Shi);
        float rlo = __builtin_amdgcn_rcpf(1.f + __builtin_amdgcn_exp2f(Slo));
        float rhi = __builtin_amdgcn_rcpf(1.f + __builtin_amdgcn_exp2f(Shi));
        float qq = rlo * g0l;
        qq = fmaf(rhi, g0h, qq);
        DPP_ADD(qq, 0xB1);   // + lane^1
        DPP_ADD(qq, 0x4E);   // + lane^2
        DPP_ADD(qq, 0x141);  // row_half_mirror -> 8-sums
        DPP_ADD(qq, 0x140);  // row_mirror      -> 16-sums
        const int qi = __float_as_int(qq);
        float ra = __int_as_float(__builtin_amdgcn_readlane(qi, 0)) +
                   __int_as_float(__builtin_amdgcn_readlane(qi, 16));
        float rb = __int_as_float(__builtin_amdgcn_readlane(qi, 32)) +
                   __int_as_float(__builtin_amdgcn_readlane(qi, 48));
        float R = ra + rb;
        float abv = __int_as_float(
            __builtin_amdgcn_readlane(__float_as_int(abrow_), s));
        float nz = fmaf(MKF, R, abv);
        float p = __builtin_amdgcn_rcpf(1.f + __builtin_amdgcn_exp2f(nz));
        pout = (lane == s) ? p : pout;
        c = p;
        // consume ring row s, refill with row s+2 (KLO scaling off-chain)
        float hl_cur = (s & 1) ? hlr1 : hlr0;
        float hh_cur = (s & 1) ? hhr1 : hhr0;
        hlp = KLO * hl_cur;
        hhp = KLO * hh_cur;
        if (s == 0 && cc == 0) { hlp = 0.f; hhp = 0.f; }  // j==0 mask
        if (s & 1) { hlr1 = hlN; hhr1 = hhN; } else { hlr0 = hlN; hhr0 = hhN; }
        g0l = g1l; g0h = g1h; g1l = g2l; g1h = g2h;
      }
      if (lane < CHUNK) out[(size_t)b * TT + cc * CHUNK + lane] = pout;
      abrow_ = abn;
    } else if (wvu >= 2) {
      if (cc + 1 < NCHUNK) produce(gbuf[(cc + 1) & 1], hT[bufn]);
    } else {
      if (cc + 2 < NCHUNK) {
        const int bufs = (bufn == 2) ? 0 : bufn + 1;
        const float* hc = hb + (size_t)(cc + 2) * CHUNK * D;
        for (int s = 0; s < CHUNK; ++s) {
          const float* hr = hc + (size_t)s * D;
          hT[bufs][lane][s] = hr[lane];
          if (lane < 36) hT[bufs][64 + lane][s] = hr[64 + lane];
        }
      }
    }
    __syncthreads();
    bufc = bufn;
  }
}

extern "C" void kernel_launch(void* const* d_in, const int* in_sizes, int n_in,
                              void* d_out, int out_size, void* d_ws, size_t ws_size,
                              hipStream_t stream) {
  const float* h   = (const float*)d_in[0];
  const float* dv  = (const float*)d_in[1];
  const float* w_c = (const float*)d_in[2];
  const float* w_s = (const float*)d_in[3];
  const float* w_r = (const float*)d_in[4];
  const float* pos = (const float*)d_in[5];
  const float* wap = (const float*)d_in[6];
  const float* bb  = (const float*)d_in[7];
  float* out = (float*)d_out;
  float* ab2m = (float*)d_ws;  // 2048 floats

  hipLaunchKernelGGL(k1_pos, dim3(TT / 256), dim3(256), 0, stream, pos, wap, bb, ab2m);
  hipLaunchKernelGGL(sp_scan, dim3(BB), dim3(NTHR), 0, stream,
                     h, dv, w_c, w_s, w_r, ab2m, out);
}

// Round 11
// 784.301 us; speedup vs baseline: 20.4877x; 1.0059x over previous
//
#include <hip/hip_runtime.h>

#define D 100
#define TT 2048
#define BB 128
#define CHUNK 32
#define NCHUNK (TT / CHUNK)  /* 64 */
#define NTHR 384             /* 6 waves: 0=consumer, 1=stager, 2..5=producers */
#define HPS 36               /* hP s-stride: 144B = 16B-aligned b128 broadcasts */

static __device__ __constant__ float KLO = 2.8853900817779268f;   // 2*log2(e)
static __device__ __constant__ float MKF = -2.8853900817779268f;  // -2*log2(e)

// q += dpp_shuffle(q); ctrl must be an immediate
#define DPP_ADD(q, ctrl)                                                      \
  q += __int_as_float(__builtin_amdgcn_update_dpp(                            \
      0, __float_as_int(q), ctrl, 0xF, 0xF, true))

// ---------------------------------------------------------------------------
// K1: ab2m[j] = -log2(e) * (pos_table[j] . w_ap + b0)
// ---------------------------------------------------------------------------
__global__ void k1_pos(const float* __restrict__ pos, const float* __restrict__ wap,
                       const float* __restrict__ bb, float* __restrict__ ab2m) {
  int j = blockIdx.x * blockDim.x + threadIdx.x;
  if (j < TT) {
    float a = 0.f;
    #pragma unroll 4
    for (int e = 0; e < D; ++e) a = fmaf(pos[j * D + e], wap[e], a);
    ab2m[j] = -1.4426950408889634f * (a + bb[0]);
  }
}

// ---------------------------------------------------------------------------
// R11 = R10 skeleton (proven allocator-stable: VGPR=88, zero spill) with the
// producer LDS traffic cut 10 instr/e -> 3 instr/e:
//   W2[e][c2] = float2{ W'[c2][e], W'[c2+64][e] }  -> one ds_read_b64 per e
//     (2-way bank alias lane/lane+16 = free).  crow lives in W2[e][36].y.
//   hP[buf][e][s], stride 36 (144B): producer reads 2x ds_read_b128 at
//     UNIFORM address (broadcast, no conflict, 16B-aligned since 144%16==0).
//     Consumer ring / stager hit bank (4*lane+s)%32 = 8-way (~6cyc) off-chain.
// R10 post-mortem: 788us was producer-LDS-pipe-bound (4000 LDS instr/chunk).
// ---------------------------------------------------------------------------
__global__ void __launch_bounds__(NTHR)
sp_scan(const float* __restrict__ h, const float* __restrict__ dv,
        const float* __restrict__ w_c, const float* __restrict__ w_s,
        const float* __restrict__ w_r, const float* __restrict__ ab2m,
        float* __restrict__ out) {
  __shared__ float2 W2[D][64];                       // 51.2 KiB
  __shared__ float gbuf[2][CHUNK][128];              // 32 KiB
  __shared__ __align__(16) float hP[3][D][HPS];      // 43.2 KiB
  const int b = blockIdx.x;
  const int tid = (int)threadIdx.x;
  const int lane = tid & 63;
  const int wvu = __builtin_amdgcn_readfirstlane(tid) >> 6;  // 0..5
  const float* hb = h + (size_t)b * TT * D;

  // ---- phase A: fill W2 (waves 0,2,3,4,5) | stager stages chunk 0 ---------
  if (wvu == 1) {
    for (int s = 0; s < CHUNK; ++s) {
      const float* hr = hb + (size_t)s * D;
      hP[0][lane][s] = hr[lane];                     // e = lane
      if (lane < 36) hP[0][64 + lane][s] = hr[64 + lane];
    }
  } else {
    const int fw = (wvu == 0) ? 0 : (wvu - 1);       // 0..4
    for (int e = fw; e < D; e += 5) {
      float wy = (lane < 36) ? w_r[(64 + lane) * D + e] : 0.f;
      W2[e][lane] = make_float2(w_r[lane * D + e], wy);
    }
  }
  __syncthreads();

  // ---- phase B: crow -> W2[e][36].y (waves 2,3) | stager stages chunk 1 ---
  if (wvu == 1) {
    const float* hc = hb + (size_t)CHUNK * D;
    for (int s = 0; s < CHUNK; ++s) {
      const float* hr = hc + (size_t)s * D;
      hP[1][lane][s] = hr[lane];
      if (lane < 36) hP[1][64 + lane][s] = hr[64 + lane];
    }
  } else if (tid >= 128 && tid < 256) {
    const int e = tid - 128;  // 0..127
    if (e < D) {
      float a1 = 0.f, a2 = 0.f;
      #pragma unroll 4
      for (int dd = 0; dd < D; ++dd) {
        a1 = fmaf(dv[b * D + dd], w_s[dd * D + e], a1);
        a2 += w_r[dd * D + e];
      }
      W2[e][36].y = w_c[e] + a1 - a2;  // synthetic row 100 = crow
    }
  }
  __syncthreads();

  // producer body: 8 s-values (s0..s0+7), cols lane & lane+64
  // per e: 1 ds_read_b64 (W) + 2 ds_read_b128 broadcasts (h) + 16 FMAs
  const int s0 = (wvu - 2) * 8;
  auto produce = [&](float (*gw)[128], const float (*hp)[HPS]) {
    float l0 = 0.f, l1 = 0.f, l2 = 0.f, l3 = 0.f,
          l4 = 0.f, l5 = 0.f, l6 = 0.f, l7 = 0.f;
    float u0 = 0.f, u1 = 0.f, u2 = 0.f, u3 = 0.f,
          u4 = 0.f, u5 = 0.f, u6 = 0.f, u7 = 0.f;
    #pragma unroll 2
    for (int e = 0; e < D; ++e) {
      const float2 w = W2[e][lane];
      const float4 hA = *(const float4*)&hp[e][s0];
      const float4 hB = *(const float4*)&hp[e][s0 + 4];
      l0 = fmaf(w.x, hA.x, l0); u0 = fmaf(w.y, hA.x, u0);
      l1 = fmaf(w.x, hA.y, l1); u1 = fmaf(w.y, hA.y, u1);
      l2 = fmaf(w.x, hA.z, l2); u2 = fmaf(w.y, hA.z, u2);
      l3 = fmaf(w.x, hA.w, l3); u3 = fmaf(w.y, hA.w, u3);
      l4 = fmaf(w.x, hB.x, l4); u4 = fmaf(w.y, hB.x, u4);
      l5 = fmaf(w.x, hB.y, l5); u5 = fmaf(w.y, hB.y, u5);
      l6 = fmaf(w.x, hB.z, l6); u6 = fmaf(w.y, hB.z, u6);
      l7 = fmaf(w.x, hB.w, l7); u7 = fmaf(w.y, hB.w, u7);
    }
    gw[s0 + 0][lane] = l0; gw[s0 + 0][64 + lane] = u0;
    gw[s0 + 1][lane] = l1; gw[s0 + 1][64 + lane] = u1;
    gw[s0 + 2][lane] = l2; gw[s0 + 2][64 + lane] = u2;
    gw[s0 + 3][lane] = l3; gw[s0 + 3][64 + lane] = u3;
    gw[s0 + 4][lane] = l4; gw[s0 + 4][64 + lane] = u4;
    gw[s0 + 5][lane] = l5; gw[s0 + 5][64 + lane] = u5;
    gw[s0 + 6][lane] = l6; gw[s0 + 6][64 + lane] = u6;
    gw[s0 + 7][lane] = l7; gw[s0 + 7][64 + lane] = u7;
  };

  // consumer state
  float Slo = 0.f, Shi = 0.f, c = 0.f, hlp = 0.f, hhp = 0.f, pout = 0.f;
  float hlr0 = 0.f, hlr1 = 0.f, hhr0 = 0.f, hhr1 = 0.f, abrow_ = 0.f;

  // ---- phase C: produce chunk 0 | consumer primes | stager idle -----------
  if (wvu == 0) {
    __builtin_amdgcn_s_setprio(1);
    abrow_ = ab2m[lane & 31];
    hlr0 = hP[0][lane][0];
    hlr1 = hP[0][lane][1];
    if (lane < 36) { hhr0 = hP[0][64 + lane][0]; hhr1 = hP[0][64 + lane][1]; }
  } else if (wvu >= 2) {
    produce(gbuf[0], hP[0]);
  }
  __syncthreads();

  // ---- main loop: 64 chunks of 32 steps -----------------------------------
  int bufc = 0;  // cc % 3
  for (int cc = 0; cc < NCHUNK; ++cc) {
    const int bufn = (bufc == 2) ? 0 : bufc + 1;
    if (wvu == 0) {
      float (*gb)[128] = gbuf[cc & 1];
      float g0l = gb[0][lane], g0h = gb[0][64 + lane];
      float g1l = gb[1][lane], g1h = gb[1][64 + lane];
      const int ncc = (cc + 1 < NCHUNK) ? cc + 1 : cc;
      float abn = ab2m[ncc * CHUNK + (lane & 31)];
      const bool notlast = (cc != NCHUNK - 1);
      #pragma unroll
      for (int s = 0; s < CHUNK; ++s) {
        // h ring refill (row s+2; crosses into next chunk's buffer)
        float hlN = 0.f, hhN = 0.f;
        if (s < CHUNK - 2) {
          hlN = hP[bufc][lane][s + 2];
          if (lane < 36) hhN = hP[bufc][64 + lane][s + 2];
        } else if (notlast) {
          hlN = hP[bufn][lane][s + 2 - CHUNK];
          if (lane < 36) hhN = hP[bufn][64 + lane][s + 2 - CHUNK];
        }
        // g prefetch, distance 2
        float g2l = 0.f, g2h = 0.f;
        if (s < CHUNK - 2) { g2l = gb[s + 2][lane]; g2h = gb[s + 2][64 + lane]; }

        // ---- the sequential chain (register/DPP only) ----
        Slo = fmaf(hlp, c, Slo);
        Shi = fmaf(hhp, c, Shi);
        float rlo = __builtin_amdgcn_rcpf(1.f + __builtin_amdgcn_exp2f(Slo));
        float rhi = __builtin_amdgcn_rcpf(1.f + __builtin_amdgcn_exp2f(Shi));
        float qq = rlo * g0l;
        qq = fmaf(rhi, g0h, qq);
        DPP_ADD(qq, 0xB1);   // + lane^1
        DPP_ADD(qq, 0x4E);   // + lane^2
        DPP_ADD(qq, 0x141);  // row_half_mirror -> 8-sums
        DPP_ADD(qq, 0x140);  // row_mirror      -> 16-sums
        const int qi = __float_as_int(qq);
        float ra = __int_as_float(__builtin_amdgcn_readlane(qi, 0)) +
                   __int_as_float(__builtin_amdgcn_readlane(qi, 16));
        float rb = __int_as_float(__builtin_amdgcn_readlane(qi, 32)) +
                   __int_as_float(__builtin_amdgcn_readlane(qi, 48));
        float R = ra + rb;
        float abv = __int_as_float(
            __builtin_amdgcn_readlane(__float_as_int(abrow_), s));
        float nz = fmaf(MKF, R, abv);
        float p = __builtin_amdgcn_rcpf(1.f + __builtin_amdgcn_exp2f(nz));
        pout = (lane == s) ? p : pout;
        c = p;
        // consume ring row s, refill with row s+2 (KLO scaling off-chain)
        float hl_cur = (s & 1) ? hlr1 : hlr0;
        float hh_cur = (s & 1) ? hhr1 : hhr0;
        hlp = KLO * hl_cur;
        hhp = KLO * hh_cur;
        if (s == 0 && cc == 0) { hlp = 0.f; hhp = 0.f; }  // j==0 mask
        if (s & 1) { hlr1 = hlN; hhr1 = hhN; } else { hlr0 = hlN; hhr0 = hhN; }
        g0l = g1l; g0h = g1h; g1l = g2l; g1h = g2h;
      }
      if (lane < CHUNK) out[(size_t)b * TT + cc * CHUNK + lane] = pout;
      abrow_ = abn;
    } else if (wvu >= 2) {
      if (cc + 1 < NCHUNK) produce(gbuf[(cc + 1) & 1], hP[bufn]);
    } else {
      if (cc + 2 < NCHUNK) {
        const int bufs = (bufn == 2) ? 0 : bufn + 1;
        const float* hc = hb + (size_t)(cc + 2) * CHUNK * D;
        for (int s = 0; s < CHUNK; ++s) {
          const float* hr = hc + (size_t)s * D;
          hP[bufs][lane][s] = hr[lane];
          if (lane < 36) hP[bufs][64 + lane][s] = hr[64 + lane];
        }
      }
    }
    __syncthreads();
    bufc = bufn;
  }
}

extern "C" void kernel_launch(void* const* d_in, const int* in_sizes, int n_in,
                              void* d_out, int out_size, void* d_ws, size_t ws_size,
                              hipStream_t stream) {
  const float* h   = (const float*)d_in[0];
  const float* dv  = (const float*)d_in[1];
  const float* w_c = (const float*)d_in[2];
  const float* w_s = (const float*)d_in[3];
  const float* w_r = (const float*)d_in[4];
  const float* pos = (const float*)d_in[5];
  const float* wap = (const float*)d_in[6];
  const float* bb  = (const float*)d_in[7];
  float* out = (float*)d_out;
  float* ab2m = (float*)d_ws;  // 2048 floats

  hipLaunchKernelGGL(k1_pos, dim3(TT / 256), dim3(256), 0, stream, pos, wap, bb, ab2m);
  hipLaunchKernelGGL(sp_scan, dim3(BB), dim3(NTHR), 0, stream,
                     h, dv, w_c, w_s, w_r, ab2m, out);
}